// Round 9
// baseline (3357.906 us; speedup 1.0000x reference)
//
#include <hip/hip_runtime.h>
#include <hip/hip_bf16.h>

typedef __bf16 bf16_t;
typedef bf16_t bf16x8 __attribute__((ext_vector_type(8)));
typedef float f32x4 __attribute__((ext_vector_type(4)));

constexpr int D_DIM = 1024;
constexpr int S_DIM = 4096;
constexpr int B_DIM = 4;

// ---------------- elementwise cast X: fp32 -> bf16 ----------------
__global__ void cast_f32_bf16(const float* __restrict__ in, bf16_t* __restrict__ out) {
  size_t i = ((size_t)blockIdx.x * blockDim.x + threadIdx.x) * 8;
  float4 a = *(const float4*)(in + i);
  float4 b = *(const float4*)(in + i + 4);
  bf16x8 o;
  o[0] = (bf16_t)a.x; o[1] = (bf16_t)a.y; o[2] = (bf16_t)a.z; o[3] = (bf16_t)a.w;
  o[4] = (bf16_t)b.x; o[5] = (bf16_t)b.y; o[6] = (bf16_t)b.z; o[7] = (bf16_t)b.w;
  *(bf16x8*)(out + i) = o;
}

// ---------------- transpose + cast weight: [1024][1024] f32 -> bf16 transposed ----
__global__ void transpose_cast_1024(const float* __restrict__ in, bf16_t* __restrict__ out) {
  __shared__ float t[32][33];
  int x0 = blockIdx.x * 32, y0 = blockIdx.y * 32;
#pragma unroll
  for (int i = 0; i < 32; i += 8)
    t[threadIdx.y + i][threadIdx.x] =
        in[(size_t)(y0 + threadIdx.y + i) * D_DIM + (x0 + threadIdx.x)];
  __syncthreads();
#pragma unroll
  for (int i = 0; i < 32; i += 8)
    out[(size_t)(x0 + threadIdx.y + i) * D_DIM + (y0 + threadIdx.x)] =
        (bf16_t)t[threadIdx.x][threadIdx.y + i];
}

// ======== 256x256 GEMM, BK=64: A via LDS dbuf (64KB), B direct global->reg ========
// 512 threads = 8 waves (2M x 4N), per-wave out 128x64 (8x4 16x16 frags).
// LDS pipe accounting: A-only LDS = 128 ds_read_b128 + 16KB write per K-tile
// (~1790 cyc) < MFMA 2483 cyc -> LDS no longer co-critical (was 2800 with B).
// B frags: 8 global_load_dwordx4 per wave per K-tile (16 rows x 64B contiguous
// per instr), L2-resident panels, double-buffered one K-tile ahead in regs.
// vmcnt ladder: phase t issues B(t+1)[8] then (after bar) A-stage(t+2)[4];
// vmcnt(4) drains exactly A(t+1)+B(t+1), keeps A(t+2) in flight.
constexpr int BM2 = 256, BN2 = 256;

#define VMCNT4 asm volatile("s_waitcnt vmcnt(4)" ::: "memory")
#define VMCNT0 asm volatile("s_waitcnt vmcnt(0)" ::: "memory")
#define LGKM0  asm volatile("s_waitcnt lgkmcnt(0)" ::: "memory")
#define SCHEDB __builtin_amdgcn_sched_barrier(0)
#define BAR __builtin_amdgcn_s_barrier()
#define PRIO1 __builtin_amdgcn_s_setprio(1)
#define PRIO0 __builtin_amdgcn_s_setprio(0)

// stage one 128-row x 64-col bf16 A-half into LDS (2 x global_load_lds, 16B/lane).
// LDS dest linear; source granule pre-swizzled (rule #21 src-side).
__device__ __forceinline__ void stage_half(const bf16_t* __restrict__ g, int ld,
                                           char* lds, int tid) {
  const int w = tid >> 6, l = tid & 63;
  const int rw = l >> 3;
  const int gl = (l & 7) ^ rw;
  char* l0 = lds + w * 1024;
  const bf16_t* s0 = g + (size_t)(w * 8 + rw) * ld + gl * 8;
  __builtin_amdgcn_global_load_lds((const __attribute__((address_space(1))) void*)s0,
                                   (__attribute__((address_space(3))) void*)l0, 16, 0, 0);
  __builtin_amdgcn_global_load_lds(
      (const __attribute__((address_space(1))) void*)(s0 + (size_t)64 * ld),
      (__attribute__((address_space(3))) void*)(l0 + 8192), 16, 0, 0);
}

// stage full A K-tile (256x64) into a slot: 4 gloads/wave
__device__ __forceinline__ void stage_a(const bf16_t* __restrict__ gA, int lda,
                                        char* slot, int tid) {
  stage_half(gA, lda, slot, tid);
  stage_half(gA + (size_t)128 * lda, lda, slot + 16384, tid);
}

// load B-frags for K-tile t directly from global into regs: 8 global_load_dwordx4
__device__ __forceinline__ void bload(const bf16_t* __restrict__ Bg, int ldb, int t,
                                      int wc, int fm, int ko, bf16x8 (&b)[4][2]) {
  const bf16_t* base = Bg + (size_t)t * 64 + ko;  // ko = (lane>>4)*8 elems
#pragma unroll
  for (int n = 0; n < 4; ++n) {
    const bf16_t* r = base + (size_t)(wc + n * 16 + fm) * ldb;
    b[n][0] = *(const bf16x8*)(r);
    b[n][1] = *(const bf16x8*)(r + 32);
  }
}

// 4 A-frags (M-set s: rows wr + s*64..+63), swizzled ds_read_b128
__device__ __forceinline__ void load_a4(const char* __restrict__ At, int wr, int fm, int s,
                                        int kx, bf16x8 (&af)[4]) {
#pragma unroll
  for (int m = 0; m < 4; ++m)
    af[m] = *(const bf16x8*)(At + (wr + (s * 4 + m) * 16 + fm) * 128 + kx);
}

// 16 independent MFMAs: 4 M-frags x 4 N-frags, one kh
__device__ __forceinline__ void mfma16(f32x4 (&acc)[8][4], const bf16x8 (&af)[4],
                                       const bf16x8 (&b)[4][2], int ms, int kh) {
#pragma unroll
  for (int m = 0; m < 4; ++m)
#pragma unroll
    for (int n = 0; n < 4; ++n)
      acc[ms * 4 + m][n] = __builtin_amdgcn_mfma_f32_16x16x32_bf16(
          af[m], b[n][kh], acc[ms * 4 + m][n], 0, 0, 0);
}

// one K-tile phase: MFMA from A-LDS slot + bcur regs; prefetch B(t+1)->bnext;
// restage A(t+2) into this slot after the mid-barrier.
template <bool HAS_NEXT_B>
__device__ __forceinline__ void kphase(
    f32x4 (&acc)[8][4], bf16x8 (&bcur)[4][2], bf16x8 (&bnext)[4][2],
    const char* __restrict__ Aslot, const bf16_t* __restrict__ Ag, int lda,
    const bf16_t* __restrict__ Bg, int ldb, int t, int NT,
    int wr, int wc, int fm, int ko, int kxa, int kxb, int tid) {
  bf16x8 af[4];
  if (HAS_NEXT_B) bload(Bg, ldb, t + 1, wc, fm, ko, bnext);

  load_a4(Aslot, wr, fm, 0, kxa, af);
  LGKM0; SCHEDB;
  PRIO1; mfma16(acc, af, bcur, 0, 0); PRIO0;
  load_a4(Aslot, wr, fm, 1, kxa, af);
  LGKM0; SCHEDB;
  PRIO1; mfma16(acc, af, bcur, 1, 0); PRIO0;
  load_a4(Aslot, wr, fm, 0, kxb, af);
  LGKM0; SCHEDB;
  PRIO1; mfma16(acc, af, bcur, 0, 1); PRIO0;
  load_a4(Aslot, wr, fm, 1, kxb, af);
  LGKM0; SCHEDB;
  PRIO1; mfma16(acc, af, bcur, 1, 1); PRIO0;

  BAR;  // all waves' reads of this A-slot are register-resident
  if (t + 2 < NT) {
    stage_a(Ag + (size_t)(t + 2) * 64, lda, (char*)Aslot, tid);
    VMCNT4;  // drain A(t+1)+B(t+1); keep A(t+2) in flight
  } else if (t + 1 < NT) {
    VMCNT0;  // tail: drain A(t+1)+B(t+1)
  }
  BAR;
}

// EPI: 0 = fused QKV (Q,K row-major + bias; V transposed + bias)
//      2 = bf16 out, sigmoid(v*scale)   (scores -> P)
//      3 = fp32 out                      (PV -> out)
template <int EPI, bool SWAP>
__global__ __launch_bounds__(512, 2) void gemm256r(
    const bf16_t* __restrict__ A, const bf16_t* __restrict__ Bt,
    void* __restrict__ C0, void* __restrict__ C1, void* __restrict__ C2,
    const float* __restrict__ b0, const float* __restrict__ b1, const float* __restrict__ b2,
    int K, int lda, int ldb, int ldc, float scale,
    size_t sA, size_t sB, size_t sC) {
  __shared__ __align__(16) char smem[65536];  // A dbuf: 2 x 32 KB

  const int tid = threadIdx.x;
  const int lane = tid & 63;
  const int w = tid >> 6;
  const int wr = (w >> 2) * 128;
  const int wc = (w & 3) * 64;
  const int fm = lane & 15;
  const int ssw = (fm & 7) << 4;
  const int kp = (lane >> 4) << 4;
  const int kxa = kp ^ ssw;          // A swizzled byte offset, kh0
  const int kxb = (64 | kp) ^ ssw;   // kh1
  const int ko = (lane >> 4) * 8;    // B element offset within 32-elem half

  // T1 bijective XCD remap (all grids have nwg % 8 == 0)
  const int nx = gridDim.x, ny = gridDim.y;
  const int nwg = nx * ny * gridDim.z;
  const int flat = blockIdx.x + nx * (blockIdx.y + ny * blockIdx.z);
  const int q = nwg >> 3;
  const int L = (flat & 7) * q + (flat >> 3);
  const int lx = L % nx;
  const int lt = L / nx;
  const int ly = lt % ny;
  const int lz = lt / ny;

  const int bx = SWAP ? ly : lx;
  const int by = SWAP ? lx : ly;

  const bf16_t* Ag = A + (size_t)lz * sA + (size_t)by * BM2 * lda;
  const bf16_t* Bg = Bt + (size_t)lz * sB + (size_t)bx * BN2 * ldb;

  f32x4 acc[8][4] = {};
  bf16x8 bA[4][2], bB[4][2];  // B reg double-buffer (named: rule #20 static idx)

  const int NT = K / 64;  // even for all our shapes (16 or 64)

  // prologue: B(0)->bA (8 loads), stage A(0)->slot0, A(1)->slot1 (8 gloads).
  // queue: [B0 x8, A0 x4, A1 x4]; vmcnt(4) drains B0+A0, keeps A1.
  bload(Bg, ldb, 0, wc, fm, ko, bA);
  stage_a(Ag, lda, smem, tid);
  stage_a(Ag + 64, lda, smem + 32768, tid);
  VMCNT4;
  BAR;

#pragma unroll 1
  for (int t = 0; t < NT; t += 2) {
    if (t + 1 < NT)
      kphase<true>(acc, bA, bB, smem, Ag, lda, Bg, ldb, t, NT,
                   wr, wc, fm, ko, kxa, kxb, tid);
    else
      kphase<false>(acc, bA, bB, smem, Ag, lda, Bg, ldb, t, NT,
                    wr, wc, fm, ko, kxa, kxb, tid);
    if (t + 2 < NT)
      kphase<true>(acc, bB, bA, smem + 32768, Ag, lda, Bg, ldb, t + 1, NT,
                   wr, wc, fm, ko, kxa, kxb, tid);
    else if (t + 1 < NT)
      kphase<false>(acc, bB, bA, smem + 32768, Ag, lda, Bg, ldb, t + 1, NT,
                    wr, wc, fm, ko, kxa, kxb, tid);
  }

  // epilogue: C/D layout col=lane&15, row=(lane>>4)*4+reg
  const int row0 = by * BM2 + wr + (lane >> 4) * 4;
  const int col0 = bx * BN2 + wc + fm;

  if constexpr (EPI == 0) {
    const int seg = bx >> 2;  // 0=Q, 1=K, 2=V
    const float* bias = (seg == 0) ? b0 : (seg == 1) ? b1 : b2;
#pragma unroll
    for (int i = 0; i < 8; ++i) {
#pragma unroll
      for (int j = 0; j < 4; ++j) {
        const int n = col0 + j * 16;
        const int nl = n & 1023;
        const float bv = bias[nl];
#pragma unroll
        for (int r = 0; r < 4; ++r) {
          const int m = row0 + i * 16 + r;
          float v = acc[i][j][r] + bv;
          if (seg < 2) {
            bf16_t* C = (bf16_t*)(seg == 0 ? C0 : C1);
            C[(size_t)m * D_DIM + nl] = (bf16_t)v;
          } else {
            // Vt[b][n][s]: b = m>>12, s = m&4095
            bf16_t* C = (bf16_t*)C2;
            C[((size_t)(m >> 12) << 22) + (size_t)nl * S_DIM + (m & (S_DIM - 1))] = (bf16_t)v;
          }
        }
      }
    }
  } else {
#pragma unroll
    for (int i = 0; i < 8; ++i) {
#pragma unroll
      for (int j = 0; j < 4; ++j) {
        const int n = col0 + j * 16;
#pragma unroll
        for (int r = 0; r < 4; ++r) {
          const int m = row0 + i * 16 + r;
          float v = acc[i][j][r];
          if constexpr (EPI == 2) {
            bf16_t* C = (bf16_t*)C0 + (size_t)lz * sC;
            float s = 1.0f / (1.0f + __expf(-v * scale));
            C[(size_t)m * ldc + n] = (bf16_t)s;
          } else {
            float* C = (float*)C0 + (size_t)lz * sC;
            C[(size_t)m * ldc + n] = v;
          }
        }
      }
    }
  }
}

extern "C" void kernel_launch(void* const* d_in, const int* in_sizes, int n_in,
                              void* d_out, int out_size, void* d_ws, size_t ws_size,
                              hipStream_t stream) {
  const float* X  = (const float*)d_in[0];
  const float* Wq = (const float*)d_in[1];
  const float* bq = (const float*)d_in[2];
  const float* Wk = (const float*)d_in[3];
  const float* bk = (const float*)d_in[4];
  const float* Wv = (const float*)d_in[5];
  const float* bv = (const float*)d_in[6];
  float* out = (float*)d_out;

  const int M = B_DIM * S_DIM;
  const size_t SD = (size_t)S_DIM * D_DIM;
  const size_t E  = (size_t)M * D_DIM;
  const size_t PE1 = (size_t)S_DIM * S_DIM;
  const size_t WE = (size_t)D_DIM * D_DIM;

  size_t need4 = (4 * PE1 + 3 * E + 3 * WE) * sizeof(bf16_t);
  const int PB = (ws_size >= need4) ? 4 : 1;
  const size_t psz = (size_t)PB * PE1;

  bf16_t* ws = (bf16_t*)d_ws;
  bf16_t* P   = ws;
  bf16_t* Xb  = ws;      // aliases P: Xb dead before first P write
  bf16_t* Qb  = ws + psz;
  bf16_t* Kb  = Qb + E;
  bf16_t* Vt  = Kb + E;  // [B][D][S]
  bf16_t* Wt  = Vt + E;  // [3072][1024]

  cast_f32_bf16<<<dim3((unsigned)(E / 8 / 256)), dim3(256), 0, stream>>>(X, Xb);

  dim3 tg(D_DIM / 32, D_DIM / 32), tb(32, 8);
  transpose_cast_1024<<<tg, tb, 0, stream>>>(Wq, Wt);
  transpose_cast_1024<<<tg, tb, 0, stream>>>(Wk, Wt + WE);
  transpose_cast_1024<<<tg, tb, 0, stream>>>(Wv, Wt + 2 * WE);

  // 3. fused QKV projection: [16384,1024] x [3072,1024]^T
  dim3 pg(3 * D_DIM / BN2, M / BM2, 1);  // (12, 64) -> 768 blocks
  gemm256r<0, false><<<pg, dim3(512), 0, stream>>>(
      Xb, Wt, Qb, Kb, Vt, bq, bk, bv, D_DIM, D_DIM, D_DIM, D_DIM, 1.0f, 0, 0, 0);

  // 4/5. scores (sigmoid fused) then PV
  const float scale = 0.03125f;  // 1/sqrt(1024)
  for (int b0 = 0; b0 < B_DIM; b0 += PB) {
    dim3 sg(S_DIM / BN2, S_DIM / BM2, PB);  // (16, 16, PB)
    gemm256r<2, false><<<sg, dim3(512), 0, stream>>>(
        Qb + (size_t)b0 * SD, Kb + (size_t)b0 * SD, P,
        nullptr, nullptr, nullptr, nullptr, nullptr,
        D_DIM, D_DIM, D_DIM, S_DIM, scale, SD, SD, PE1);
    dim3 vg(S_DIM / BM2, D_DIM / BN2, PB);  // (16, 4, PB)
    gemm256r<3, true><<<vg, dim3(512), 0, stream>>>(
        P, Vt + (size_t)b0 * SD, out + (size_t)b0 * SD,
        nullptr, nullptr, nullptr, nullptr, nullptr,
        S_DIM, S_DIM, S_DIM, D_DIM, 1.0f, PE1, SD, SD);
  }
}